// Round 1
// baseline (246.265 us; speedup 1.0000x reference)
//
#include <hip/hip_runtime.h>
#include <math.h>

#define NB      512
#define NELEC   30
#define NATOMS  10
#define NNEN    40      // en graph nodes: 30 electrons + 10 atoms
#define FEAT    64
#define KRBF    64
#define BLOCK   512
#define NWAVES  (BLOCK/64)
#define NPEE    435     // unique elec-elec pairs
#define NPEN    300     // unique elec-nuc pairs
#define FPAD    65      // filt row padding (+1 float) to break bank conflicts

// ---------------- LDS layouts (in floats) ----------------
// ee: xyz[96] | h[30*64] | agg[30*64] | filt[435*65]
#define EE_H     96
#define EE_AGG   (EE_H + NELEC*FEAT)
#define EE_FILT  (EE_AGG + NELEC*FEAT)
#define EE_TOTAL (EE_FILT + NPEE*FPAD)          // 32659 floats = 130636 B
// en: xyz[96] | h[40*64] | agg[40*64] | filt[300*65]
#define EN_H     96
#define EN_AGG   (EN_H + NNEN*FEAT)
#define EN_FILT  (EN_AGG + NNEN*FEAT)
#define EN_TOTAL (EN_FILT + NPEN*FPAD)          // 24716 floats = 98864 B

// triangular pair index base for row i (i<j pairs of 30 electrons)
__device__ __forceinline__ int ee_base(int i) { return 29*i - ((i*(i-1))>>1); }

// ==========================================================================
// elec-elec GNN: one block per batch. Writes partial log-Jastrow (double).
// ==========================================================================
__global__ __launch_bounds__(BLOCK)
void ee_kernel(const float* __restrict__ pos,
               const float* __restrict__ emb,
               const float* __restrict__ wf,
               const float* __restrict__ bf,
               const float* __restrict__ wl,
               const float* __restrict__ bl,
               const float* __restrict__ wr,
               const float* __restrict__ br,
               const int*   __restrict__ types,
               double*      __restrict__ kout)
{
    extern __shared__ float sm[];
    float* xyz  = sm;           // [96]
    float* hS   = sm + EE_H;    // [30][64]
    float* aggS = sm + EE_AGG;  // [30][64]
    float* fS   = sm + EE_FILT; // [435][65]

    const int tid  = threadIdx.x;
    const int b    = blockIdx.x;
    const int lane = tid & 63;
    const int w    = tid >> 6;

    // stage positions; init h = emb[types]
    for (int idx = tid; idx < NELEC*3; idx += BLOCK) xyz[idx] = pos[b*NELEC*3 + idx];
    for (int idx = tid; idx < NELEC*FEAT; idx += BLOCK) {
        int n = idx >> 6, f = idx & 63;
        hS[idx] = emb[types[n]*FEAT + f];
    }
    __syncthreads();

    // ---- filter GEMM: one unique pair per lane (clamped -> uniform CF) ----
    {
        const int p = (tid < NPEE) ? tid : (NPEE - 1);
        int i = 0, rem = p;
        while (rem >= NELEC - 1 - i) { rem -= NELEC - 1 - i; ++i; }
        const int j = i + 1 + rem;
        const float dx = xyz[3*i+0] - xyz[3*j+0];
        const float dy = xyz[3*i+1] - xyz[3*j+1];
        const float dz = xyz[3*i+2] - xyz[3*j+2];
        const float dd = sqrtf(dx*dx + dy*dy + dz*dz);

        float acc[FEAT];
        #pragma unroll
        for (int f = 0; f < FEAT; ++f) acc[f] = bf[f];   // uniform -> s_load
        #pragma unroll 2
        for (int k = 0; k < KRBF; ++k) {
            const float ck = (float)((double)k * (8.0/63.0));
            const float t  = dd - ck;
            const float rk = expf(-t*t);
            const float* wrow = wf + k*FEAT;             // wave-uniform row
            #pragma unroll
            for (int f = 0; f < FEAT; ++f) acc[f] = fmaf(rk, wrow[f], acc[f]);
        }
        #pragma unroll
        for (int f = 0; f < FEAT; ++f) fS[p*FPAD + f] = tanhf(acc[f]);
    }
    __syncthreads();

    // ---- interaction layers ----
    for (int l = 0; l < 2; ++l) {
        const float* wlL = wl + l*FEAT*FEAT;
        const float* blL = bl + l*FEAT;
        float hreg[NELEC];
        #pragma unroll
        for (int j = 0; j < NELEC; ++j) hreg[j] = hS[j*FEAT + lane];
        float wlc[FEAT];
        #pragma unroll
        for (int k = 0; k < FEAT; ++k) wlc[k] = wlL[k*FEAT + lane];

        // messages: agg[i] = sum_{j!=i} h[j] * filt[pair(i,j)]  (j ascending = ref order)
        for (int i = w; i < NELEC; i += NWAVES) {
            float a = 0.f;
            #pragma unroll
            for (int j = 0; j < NELEC; ++j) {
                if (j != i) {
                    int p = (j < i) ? (ee_base(j) + (i - j - 1))
                                    : (ee_base(i) + (j - i - 1));
                    a = fmaf(hreg[j], fS[p*FPAD + lane], a);
                }
            }
            aggS[i*FEAT + lane] = a;
        }
        __syncthreads();

        // h += tanh(agg @ wl + bl)
        for (int i = w; i < NELEC; i += NWAVES) {
            float a2 = 0.f;
            const float4* arow = reinterpret_cast<const float4*>(aggS + i*FEAT);
            #pragma unroll
            for (int k = 0; k < FEAT/4; ++k) {
                float4 av = arow[k];                      // broadcast b128
                a2 = fmaf(av.x, wlc[4*k+0], a2);
                a2 = fmaf(av.y, wlc[4*k+1], a2);
                a2 = fmaf(av.z, wlc[4*k+2], a2);
                a2 = fmaf(av.w, wlc[4*k+3], a2);
            }
            hS[i*FEAT + lane] += tanhf(a2 + blL[lane]);
        }
        __syncthreads();
    }

    // ---- readout: (sum_n h[n]) . wr + br   (f64 tail) ----
    if (w == 0) {
        float s = 0.f;
        #pragma unroll
        for (int n = 0; n < NELEC; ++n) s += hS[n*FEAT + lane];
        double dv = (double)s * (double)wr[lane];
        #pragma unroll
        for (int o = 32; o > 0; o >>= 1) dv += __shfl_xor(dv, o, 64);
        if (lane == 0) kout[b] = dv + (double)br[0];
    }
}

// ==========================================================================
// elec-nuc GNN + final combine: out[b] = exp(k_ee + k_en)
// ==========================================================================
__global__ __launch_bounds__(BLOCK)
void en_kernel(const float* __restrict__ pos,
               const float* __restrict__ atoms,
               const float* __restrict__ emb,
               const float* __restrict__ wf,
               const float* __restrict__ bf,
               const float* __restrict__ wl,
               const float* __restrict__ bl,
               const float* __restrict__ wr,
               const float* __restrict__ br,
               const int*   __restrict__ types,
               const double* __restrict__ kin,
               float*       __restrict__ out)
{
    extern __shared__ float sm[];
    float* xyz  = sm;           // [96]
    float* hS   = sm + EN_H;    // [40][64]
    float* aggS = sm + EN_AGG;  // [40][64]
    float* fS   = sm + EN_FILT; // [300][65]

    const int tid  = threadIdx.x;
    const int b    = blockIdx.x;
    const int lane = tid & 63;
    const int w    = tid >> 6;

    for (int idx = tid; idx < NELEC*3; idx += BLOCK) xyz[idx] = pos[b*NELEC*3 + idx];
    for (int idx = tid; idx < NNEN*FEAT; idx += BLOCK) {
        int n = idx >> 6, f = idx & 63;
        hS[idx] = emb[types[n]*FEAT + f];
    }
    __syncthreads();

    // ---- filter GEMM: pair q = a*30 + e (atom-major, matches ref ordering) ----
    {
        const int p = (tid < NPEN) ? tid : (NPEN - 1);
        const int a = p / NELEC;
        const int e = p - a*NELEC;
        const float dx = xyz[3*e+0] - atoms[3*a+0];
        const float dy = xyz[3*e+1] - atoms[3*a+1];
        const float dz = xyz[3*e+2] - atoms[3*a+2];
        const float dd = sqrtf(dx*dx + dy*dy + dz*dz);

        float acc[FEAT];
        #pragma unroll
        for (int f = 0; f < FEAT; ++f) acc[f] = bf[f];
        #pragma unroll 2
        for (int k = 0; k < KRBF; ++k) {
            const float ck = (float)((double)k * (8.0/63.0));
            const float t  = dd - ck;
            const float rk = expf(-t*t);
            const float* wrow = wf + k*FEAT;
            #pragma unroll
            for (int f = 0; f < FEAT; ++f) acc[f] = fmaf(rk, wrow[f], acc[f]);
        }
        #pragma unroll
        for (int f = 0; f < FEAT; ++f) fS[p*FPAD + f] = tanhf(acc[f]);
    }
    __syncthreads();

    for (int l = 0; l < 2; ++l) {
        const float* wlL = wl + l*FEAT*FEAT;
        const float* blL = bl + l*FEAT;
        float hreg[NNEN];
        #pragma unroll
        for (int j = 0; j < NNEN; ++j) hreg[j] = hS[j*FEAT + lane];
        float wlc[FEAT];
        #pragma unroll
        for (int k = 0; k < FEAT; ++k) wlc[k] = wlL[k*FEAT + lane];

        // messages (bipartite)
        for (int n = w; n < NNEN; n += NWAVES) {
            float a = 0.f;
            if (n < NELEC) {           // electron node: sum over atoms (a ascending)
                #pragma unroll
                for (int at = 0; at < NATOMS; ++at)
                    a = fmaf(hreg[NELEC+at], fS[(at*NELEC + n)*FPAD + lane], a);
            } else {                   // atom node: sum over electrons (e ascending)
                const int at = n - NELEC;
                #pragma unroll
                for (int e2 = 0; e2 < NELEC; ++e2)
                    a = fmaf(hreg[e2], fS[(at*NELEC + e2)*FPAD + lane], a);
            }
            aggS[n*FEAT + lane] = a;
        }
        __syncthreads();

        for (int n = w; n < NNEN; n += NWAVES) {
            float a2 = 0.f;
            const float4* arow = reinterpret_cast<const float4*>(aggS + n*FEAT);
            #pragma unroll
            for (int k = 0; k < FEAT/4; ++k) {
                float4 av = arow[k];
                a2 = fmaf(av.x, wlc[4*k+0], a2);
                a2 = fmaf(av.y, wlc[4*k+1], a2);
                a2 = fmaf(av.z, wlc[4*k+2], a2);
                a2 = fmaf(av.w, wlc[4*k+3], a2);
            }
            hS[n*FEAT + lane] += tanhf(a2 + blL[lane]);
        }
        __syncthreads();
    }

    if (w == 0) {
        float s = 0.f;
        #pragma unroll
        for (int n = 0; n < NNEN; ++n) s += hS[n*FEAT + lane];
        double dv = (double)s * (double)wr[lane];
        #pragma unroll
        for (int o = 32; o > 0; o >>= 1) dv += __shfl_xor(dv, o, 64);
        if (lane == 0) out[b] = (float)exp(dv + (double)br[0] + kin[b]);
    }
}

// ==========================================================================
extern "C" void kernel_launch(void* const* d_in, const int* in_sizes, int n_in,
                              void* d_out, int out_size, void* d_ws, size_t ws_size,
                              hipStream_t stream) {
    const float* pos    = (const float*)d_in[0];
    const float* atoms  = (const float*)d_in[1];
    const float* emb_ee = (const float*)d_in[2];
    const float* wf_ee  = (const float*)d_in[3];
    const float* bf_ee  = (const float*)d_in[4];
    const float* wl_ee  = (const float*)d_in[5];
    const float* bl_ee  = (const float*)d_in[6];
    const float* wr_ee  = (const float*)d_in[7];
    const float* br_ee  = (const float*)d_in[8];
    const float* emb_en = (const float*)d_in[9];
    const float* wf_en  = (const float*)d_in[10];
    const float* bf_en  = (const float*)d_in[11];
    const float* wl_en  = (const float*)d_in[12];
    const float* bl_en  = (const float*)d_in[13];
    const float* wr_en  = (const float*)d_in[14];
    const float* br_en  = (const float*)d_in[15];
    const int*   ee_ty  = (const int*)d_in[18];
    const int*   en_ty  = (const int*)d_in[21];

    double* kws = (double*)d_ws;       // [512] partial log-Jastrow from ee
    float*  out = (float*)d_out;       // [512]

    // opt in to >64KB dynamic LDS (160 KB/CU on gfx950); capture-safe host call
    (void)hipFuncSetAttribute((const void*)ee_kernel,
            hipFuncAttributeMaxDynamicSharedMemorySize, EE_TOTAL*(int)sizeof(float));
    (void)hipFuncSetAttribute((const void*)en_kernel,
            hipFuncAttributeMaxDynamicSharedMemorySize, EN_TOTAL*(int)sizeof(float));

    ee_kernel<<<NB, BLOCK, EE_TOTAL*sizeof(float), stream>>>(
        pos, emb_ee, wf_ee, bf_ee, wl_ee, bl_ee, wr_ee, br_ee, ee_ty, kws);
    en_kernel<<<NB, BLOCK, EN_TOTAL*sizeof(float), stream>>>(
        pos, atoms, emb_en, wf_en, bf_en, wl_en, bl_en, wr_en, br_en, en_ty, kws, out);
}